// Round 8
// baseline (15596.692 us; speedup 1.0000x reference)
//
#include <hip/hip_runtime.h>

#define TT 4096

typedef __attribute__((ext_vector_type(2))) unsigned int u2v;
typedef __attribute__((ext_vector_type(4))) unsigned int u4v;
typedef __attribute__((ext_vector_type(2))) __fp16 f16x2;
typedef __attribute__((ext_vector_type(2))) _Float16 F16x2;
union HU { unsigned int u; f16x2 hf; F16x2 hF; };

// ws layout (float offsets):
//   M    @ 0      : 2048*64 = 131072   (W_in @ C)
//   wtil @ 131072 : 64                 (C^T @ dense_W[:64])
//   yp   @ 131200 : 4096*64 = 262144   (per-WG dense partials, plain stores)
//   hpub @ 393344 : 2 slots * 1024 packets * (u32 data, u32 tag) = 4096 u32
// hpub needs NO init: harness poisons ws to 0xAA -> tag never matches t+1.
//
// LAW (r1/r2/r6, 3x confirmed): publish MUST be one coalesced wave-wide
// store burst from ONE wave after a gather barrier.
// FALSIFIED (r2/r4): reader-per-line contention. (r7): poll sampling
// quantization; barrier vmcnt drains.
// r8 THEORY: detect waits on cross-L2 invalidation propagation. Evidence:
// FETCH/step = 36.9 KB < one full-board EA-refetch (64 KB) -> sc0sc1 poll
// rounds are served stale by XCD-local L2 until the remote write's
// invalidation lands. Fix: `nt` on publish + poll -> board lives at the
// coherence point (MALL), polls read it directly each round.

__global__ void esn_prep(const float* __restrict__ C,
                         const float* __restrict__ Win,
                         const float* __restrict__ dW,
                         float* __restrict__ M,
                         float* __restrict__ wtil) {
  __shared__ float s[64];
  const int b = blockIdx.x, i = threadIdx.x;
  if (b < 2048) {
    s[i] = Win[b * 64 + i];
    __syncthreads();
    float acc = 0.f;
#pragma unroll 16
    for (int d = 0; d < 64; ++d) acc += s[d] * C[d * 64 + i];
    M[b * 64 + i] = acc;
  } else {
    s[i] = dW[i];
    __syncthreads();
    float acc = 0.f;
    for (int d = 0; d < 64; ++d) acc += s[d] * C[d * 64 + i];
    wtil[i] = acc;
  }
}

// Call-free tanh: tanh(x) = 1 - 2/(exp(2x)+1)
__device__ __forceinline__ float fast_tanh(float x) {
  const float e = __builtin_amdgcn_exp2f(x * 2.8853900817779268f);  // exp(2x)
  return 1.0f - 2.0f * __builtin_amdgcn_rcpf(e + 1.0f);
}

// fp16-pair dot with fp32 accumulate: v_dot2_f32_f16 where available.
__device__ __forceinline__ float fdot2f(const HU a, const HU b, float c) {
#if __has_builtin(__builtin_amdgcn_fdot2)
  return __builtin_amdgcn_fdot2(a.hF, b.hF, c, false);
#else
  return c + (float)a.hf.x * (float)b.hf.x + (float)a.hf.y * (float)b.hf.y;
#endif
}

// 64 WGs x 1024 threads; WG owns 32 rows (2/wave); W in VGPRs.
// Identical to the 9629 us r3 kernel EXCEPT: publish stores and poll loads
// carry `nt` (non-temporal) in addition to sc0 sc1 -- single-variable test
// of the invalidation-propagation theory.
__global__ __launch_bounds__(1024) void esn_recur(
    const float* __restrict__ X, const float* __restrict__ M,
    const float* __restrict__ W, const float* __restrict__ dW,
    unsigned int* __restrict__ hpub, float* __restrict__ yp) {
  __shared__ unsigned int shh[1024];  // 2048 fp16 h as packed pairs
  __shared__ unsigned int pub[16];    // per-wave packed h pairs
  __shared__ float psm[16];           // per-wave dense partials
  const int tid = threadIdx.x;
  const int lane = tid & 63;
  const int wave = tid >> 6;
  const int b = blockIdx.x;
  const int r0 = b * 32 + wave * 2;
  const float m0 = M[r0 * 64 + lane];
  const float m1 = M[(r0 + 1) * 64 + lane];
  const float dw0 = dW[64 + r0];
  const float dw1 = dW[64 + r0 + 1];
  // one-time: this lane's W fragment -> 32 persistent VGPRs (packed fp16).
  u4v wA[4], wB[4];
#pragma unroll
  for (int j = 0; j < 4; ++j) {
    const float* p0 = W + (size_t)r0 * 2048 + 512 * j + 8 * lane;
    const float* p1 = p0 + 2048;
    const float4 a = *(const float4*)p0;
    const float4 c = *(const float4*)(p0 + 4);
    const float4 d = *(const float4*)p1;
    const float4 e = *(const float4*)(p1 + 4);
    HU t0, t1, t2, t3;
    t0.hf = __builtin_amdgcn_cvt_pkrtz(a.x, a.y);
    t1.hf = __builtin_amdgcn_cvt_pkrtz(a.z, a.w);
    t2.hf = __builtin_amdgcn_cvt_pkrtz(c.x, c.y);
    t3.hf = __builtin_amdgcn_cvt_pkrtz(c.z, c.w);
    wA[j][0] = t0.u; wA[j][1] = t1.u; wA[j][2] = t2.u; wA[j][3] = t3.u;
    t0.hf = __builtin_amdgcn_cvt_pkrtz(d.x, d.y);
    t1.hf = __builtin_amdgcn_cvt_pkrtz(d.z, d.w);
    t2.hf = __builtin_amdgcn_cvt_pkrtz(e.x, e.y);
    t3.hf = __builtin_amdgcn_cvt_pkrtz(e.z, e.w);
    wB[j][0] = t0.u; wB[j][1] = t1.u; wB[j][2] = t2.u; wB[j][3] = t3.u;
  }
  shh[tid] = 0u;  // h_{-1} = 0
  __syncthreads();

  float xv = X[lane];

  for (int t = 0; t < TT; ++t) {
    // ---- compute 2 rows/wave: W from VGPR, h from LDS ----
    float a0 = m0 * xv, a1 = m1 * xv;
#pragma unroll
    for (int j = 0; j < 4; ++j) {
      const u4v hv = *(const u4v*)(shh + 4 * lane + 256 * j);
#pragma unroll
      for (int k = 0; k < 4; ++k) {
        HU ha, wa, wb;
        ha.u = hv[k]; wa.u = wA[j][k]; wb.u = wB[j][k];
        a0 = fdot2f(wa, ha, a0);
        a1 = fdot2f(wb, ha, a1);
      }
    }
#pragma unroll
    for (int off = 32; off; off >>= 1) {
      a0 += __shfl_xor(a0, off, 64);
      a1 += __shfl_xor(a1, off, 64);
    }
    const int tn = (t + 1 < TT) ? t + 1 : t;
    const float xnext = X[tn * 64 + lane];  // prefetch: hides under poll
    if (lane == 0) {
      const float h0 = fast_tanh(a0);
      const float h1 = fast_tanh(a1);
      HU pk; pk.hf = __builtin_amdgcn_cvt_pkrtz(h0, h1);
      pub[wave] = pk.u;
      psm[wave] = dw0 * h0 + dw1 * h1;
    }
    __syncthreads();  // pub + psm ready; all shh reads of step t done
    const unsigned tg = (unsigned)t + 1u;
    if (wave == 0) {
      if (t + 1 < TT) {
        unsigned int* slot = hpub + ((t & 1) << 11);
        // publish: ONE coalesced 16-packet burst, MALL-direct (nt)
        if (tid < 16) {
          u2v pv; pv.x = pub[tid]; pv.y = tg;
          asm volatile("global_store_dwordx2 %0, %1, off sc0 sc1 nt"
                       :: "v"(slot + 2 * (16 * b + tid)), "v"(pv) : "memory");
        }
        // poll: lane L owns packets {64p+L}; 16 loads in flight per round,
        // each round reads the coherence point directly (nt).
        const unsigned int* b0 = slot + 2 * lane;
        const unsigned int* b1 = b0 + 1024;
        u2v q0, q1, q2, q3, q4, q5, q6, q7, q8, q9, qa, qb, qc, qd, qe, qf;
        for (;;) {
          asm volatile(
              "global_load_dwordx2 %0, %16, off sc0 sc1 nt\n\t"
              "global_load_dwordx2 %1, %16, off offset:512 sc0 sc1 nt\n\t"
              "global_load_dwordx2 %2, %16, off offset:1024 sc0 sc1 nt\n\t"
              "global_load_dwordx2 %3, %16, off offset:1536 sc0 sc1 nt\n\t"
              "global_load_dwordx2 %4, %16, off offset:2048 sc0 sc1 nt\n\t"
              "global_load_dwordx2 %5, %16, off offset:2560 sc0 sc1 nt\n\t"
              "global_load_dwordx2 %6, %16, off offset:3072 sc0 sc1 nt\n\t"
              "global_load_dwordx2 %7, %16, off offset:3584 sc0 sc1 nt\n\t"
              "global_load_dwordx2 %8, %17, off sc0 sc1 nt\n\t"
              "global_load_dwordx2 %9, %17, off offset:512 sc0 sc1 nt\n\t"
              "global_load_dwordx2 %10, %17, off offset:1024 sc0 sc1 nt\n\t"
              "global_load_dwordx2 %11, %17, off offset:1536 sc0 sc1 nt\n\t"
              "global_load_dwordx2 %12, %17, off offset:2048 sc0 sc1 nt\n\t"
              "global_load_dwordx2 %13, %17, off offset:2560 sc0 sc1 nt\n\t"
              "global_load_dwordx2 %14, %17, off offset:3072 sc0 sc1 nt\n\t"
              "global_load_dwordx2 %15, %17, off offset:3584 sc0 sc1 nt\n\t"
              "s_waitcnt vmcnt(0)"
              : "=&v"(q0), "=&v"(q1), "=&v"(q2), "=&v"(q3),
                "=&v"(q4), "=&v"(q5), "=&v"(q6), "=&v"(q7),
                "=&v"(q8), "=&v"(q9), "=&v"(qa), "=&v"(qb),
                "=&v"(qc), "=&v"(qd), "=&v"(qe), "=&v"(qf)
              : "v"(b0), "v"(b1)
              : "memory");
          bool ok = (q0.y == tg) && (q1.y == tg) && (q2.y == tg) &&
                    (q3.y == tg) && (q4.y == tg) && (q5.y == tg) &&
                    (q6.y == tg) && (q7.y == tg) && (q8.y == tg) &&
                    (q9.y == tg) && (qa.y == tg) && (qb.y == tg) &&
                    (qc.y == tg) && (qd.y == tg) && (qe.y == tg) &&
                    (qf.y == tg);
          if (__all(ok)) break;
        }
        // repack: shh[64p + lane] -- stride-1 across lanes, conflict-free
        shh[lane] = q0.x;          shh[64 + lane] = q1.x;
        shh[128 + lane] = q2.x;    shh[192 + lane] = q3.x;
        shh[256 + lane] = q4.x;    shh[320 + lane] = q5.x;
        shh[384 + lane] = q6.x;    shh[448 + lane] = q7.x;
        shh[512 + lane] = q8.x;    shh[576 + lane] = q9.x;
        shh[640 + lane] = qa.x;    shh[704 + lane] = qb.x;
        shh[768 + lane] = qc.x;    shh[832 + lane] = qd.x;
        shh[896 + lane] = qe.x;    shh[960 + lane] = qf.x;
      }
    } else if (tid == 64) {
      // dense partial for step t (parallel with wave0's protocol)
      float s = 0.f;
#pragma unroll
      for (int wv = 0; wv < 16; ++wv) s += psm[wv];
      yp[t * 64 + b] = s;
    }
    __syncthreads();  // shh now holds h_t
    xv = xnext;
  }
}

__global__ void esn_out(const float* __restrict__ X,
                        const float* __restrict__ wtil,
                        const float* __restrict__ yp,
                        const float* __restrict__ bptr,
                        float* __restrict__ out) {
  const int tid = threadIdx.x;
  const int lane = tid & 63;
  const int wave = tid >> 6;
  const int t = blockIdx.x * 4 + wave;
  float v = wtil[lane] * X[t * 64 + lane] + yp[t * 64 + lane];
#pragma unroll
  for (int off = 32; off; off >>= 1) v += __shfl_xor(v, off, 64);
  if (lane == 0) out[t] = v + bptr[0];
}

extern "C" void kernel_launch(void* const* d_in, const int* in_sizes, int n_in,
                              void* d_out, int out_size, void* d_ws, size_t ws_size,
                              hipStream_t stream) {
  const float* X   = (const float*)d_in[0];
  const float* C   = (const float*)d_in[1];
  const float* Win = (const float*)d_in[2];
  const float* W   = (const float*)d_in[3];
  const float* dW  = (const float*)d_in[4];
  const float* db  = (const float*)d_in[5];
  float* ws   = (float*)d_ws;
  float* M    = ws;
  float* wtil = ws + 131072;
  float* yp   = ws + 131200;
  unsigned int* hpub = (unsigned int*)(ws + 393344);

  esn_prep<<<2049, 64, 0, stream>>>(C, Win, dW, M, wtil);

  void* args[] = {(void*)&X, (void*)&M, (void*)&W, (void*)&dW,
                  (void*)&hpub, (void*)&yp};
  (void)hipLaunchCooperativeKernel(reinterpret_cast<void*>(&esn_recur), dim3(64),
                                   dim3(1024), args, 0, stream);

  esn_out<<<1024, 256, 0, stream>>>(X, wtil, yp, db, (float*)d_out);
}

// Round 9
// 9116.441 us; speedup vs baseline: 1.7108x; 1.7108x over previous
//
#include <hip/hip_runtime.h>

#define TT 4096

typedef __attribute__((ext_vector_type(2))) unsigned int u2v;
typedef __attribute__((ext_vector_type(4))) unsigned int u4v;
typedef __attribute__((ext_vector_type(2))) __fp16 f16x2;
typedef __attribute__((ext_vector_type(2))) _Float16 F16x2;
union HU { unsigned int u; f16x2 hf; F16x2 hF; };

// ws layout (float offsets):
//   M    @ 0      : 2048*64 = 131072   (W_in @ C)
//   wtil @ 131072 : 64                 (C^T @ dense_W[:64])
//   yp   @ 131200 : 4096*64 = 262144   (per-WG dense partials, plain stores)
//   hpub @ 393344 : 2 slots * 1024 packets * (u32 data, u32 tag) = 4096 u32
// hpub needs NO init: harness poisons ws to 0xAA -> tag never matches t+1.
//
// LAW (r1/r2/r6, 3x): publish = ONE coalesced wave-wide burst from ONE wave
// after a gather barrier. FALSIFIED: reader contention (r2/r4), poll
// sampling quantization (r7), nt/MALL-direct (r8 -- regressed 1.6x).
// r9 THEORY: in r3 the SAME wave stores then polls; every poll round's
// vmcnt(0) drain waits the system-scope store ACK (cross-die, ~2-3x load
// RT) before the next sample issues. Split publisher (wave1) from poller
// (wave0): poller's queue never holds a store; publish overlaps poll.

__global__ void esn_prep(const float* __restrict__ C,
                         const float* __restrict__ Win,
                         const float* __restrict__ dW,
                         float* __restrict__ M,
                         float* __restrict__ wtil) {
  __shared__ float s[64];
  const int b = blockIdx.x, i = threadIdx.x;
  if (b < 2048) {
    s[i] = Win[b * 64 + i];
    __syncthreads();
    float acc = 0.f;
#pragma unroll 16
    for (int d = 0; d < 64; ++d) acc += s[d] * C[d * 64 + i];
    M[b * 64 + i] = acc;
  } else {
    s[i] = dW[i];
    __syncthreads();
    float acc = 0.f;
    for (int d = 0; d < 64; ++d) acc += s[d] * C[d * 64 + i];
    wtil[i] = acc;
  }
}

// Call-free tanh: tanh(x) = 1 - 2/(exp(2x)+1)
__device__ __forceinline__ float fast_tanh(float x) {
  const float e = __builtin_amdgcn_exp2f(x * 2.8853900817779268f);  // exp(2x)
  return 1.0f - 2.0f * __builtin_amdgcn_rcpf(e + 1.0f);
}

// fp16-pair dot with fp32 accumulate: v_dot2_f32_f16 where available.
__device__ __forceinline__ float fdot2f(const HU a, const HU b, float c) {
#if __has_builtin(__builtin_amdgcn_fdot2)
  return __builtin_amdgcn_fdot2(a.hF, b.hF, c, false);
#else
  return c + (float)a.hf.x * (float)b.hf.x + (float)a.hf.y * (float)b.hf.y;
#endif
}

// 64 WGs x 1024 threads; WG owns 32 rows (2/wave); W in VGPRs (r3 proven).
// v9 = r3 byte-identical EXCEPT:
//  * PUBLISHER/POLLER SPLIT: wave1 (lanes 0-15) fires the coalesced
//    16-packet burst; wave0 only polls. wave0's per-round vmcnt(0) now
//    drains ONLY its 16 loads (+ the already-in-flight X prefetch in round
//    1) -- never a store ack. Publish store completes in wave1's queue,
//    drained at bar2 where wave1 is an EARLY arriver (wave0, arriving
//    ~detect-time later, sets the barrier release; ack wait is hidden).
//  * X PREFETCH AFTER BAR1: issued at the start of the exchange phase, so
//    its latency hides under the poll (wave0) or under bar2 slack (idle
//    waves) instead of stalling bar1's vmcnt(0) drain.
//  * yp partial moved to wave2 lane0 (tid 128): keeps wave1 store-only.
__global__ __launch_bounds__(1024) void esn_recur(
    const float* __restrict__ X, const float* __restrict__ M,
    const float* __restrict__ W, const float* __restrict__ dW,
    unsigned int* __restrict__ hpub, float* __restrict__ yp) {
  __shared__ unsigned int shh[1024];  // 2048 fp16 h as packed pairs
  __shared__ unsigned int pub[16];    // per-wave packed h pairs
  __shared__ float psm[16];           // per-wave dense partials
  const int tid = threadIdx.x;
  const int lane = tid & 63;
  const int wave = tid >> 6;
  const int b = blockIdx.x;
  const int r0 = b * 32 + wave * 2;
  const float m0 = M[r0 * 64 + lane];
  const float m1 = M[(r0 + 1) * 64 + lane];
  const float dw0 = dW[64 + r0];
  const float dw1 = dW[64 + r0 + 1];
  // one-time: this lane's W fragment -> 32 persistent VGPRs (packed fp16).
  u4v wA[4], wB[4];
#pragma unroll
  for (int j = 0; j < 4; ++j) {
    const float* p0 = W + (size_t)r0 * 2048 + 512 * j + 8 * lane;
    const float* p1 = p0 + 2048;
    const float4 a = *(const float4*)p0;
    const float4 c = *(const float4*)(p0 + 4);
    const float4 d = *(const float4*)p1;
    const float4 e = *(const float4*)(p1 + 4);
    HU t0, t1, t2, t3;
    t0.hf = __builtin_amdgcn_cvt_pkrtz(a.x, a.y);
    t1.hf = __builtin_amdgcn_cvt_pkrtz(a.z, a.w);
    t2.hf = __builtin_amdgcn_cvt_pkrtz(c.x, c.y);
    t3.hf = __builtin_amdgcn_cvt_pkrtz(c.z, c.w);
    wA[j][0] = t0.u; wA[j][1] = t1.u; wA[j][2] = t2.u; wA[j][3] = t3.u;
    t0.hf = __builtin_amdgcn_cvt_pkrtz(d.x, d.y);
    t1.hf = __builtin_amdgcn_cvt_pkrtz(d.z, d.w);
    t2.hf = __builtin_amdgcn_cvt_pkrtz(e.x, e.y);
    t3.hf = __builtin_amdgcn_cvt_pkrtz(e.z, e.w);
    wB[j][0] = t0.u; wB[j][1] = t1.u; wB[j][2] = t2.u; wB[j][3] = t3.u;
  }
  shh[tid] = 0u;  // h_{-1} = 0
  __syncthreads();

  float xv = X[lane];

  for (int t = 0; t < TT; ++t) {
    // ---- compute 2 rows/wave: W from VGPR, h from LDS ----
    float a0 = m0 * xv, a1 = m1 * xv;
#pragma unroll
    for (int j = 0; j < 4; ++j) {
      const u4v hv = *(const u4v*)(shh + 4 * lane + 256 * j);
#pragma unroll
      for (int k = 0; k < 4; ++k) {
        HU ha, wa, wb;
        ha.u = hv[k]; wa.u = wA[j][k]; wb.u = wB[j][k];
        a0 = fdot2f(wa, ha, a0);
        a1 = fdot2f(wb, ha, a1);
      }
    }
#pragma unroll
    for (int off = 32; off; off >>= 1) {
      a0 += __shfl_xor(a0, off, 64);
      a1 += __shfl_xor(a1, off, 64);
    }
    if (lane == 0) {
      const float h0 = fast_tanh(a0);
      const float h1 = fast_tanh(a1);
      HU pk; pk.hf = __builtin_amdgcn_cvt_pkrtz(h0, h1);
      pub[wave] = pk.u;
      psm[wave] = dw0 * h0 + dw1 * h1;
    }
    __syncthreads();  // bar1: pub + psm ready; all shh reads of step t done
    const unsigned tg = (unsigned)t + 1u;
    unsigned int* slot = hpub + ((t & 1) << 11);
    // X prefetch for t+1: issued at exchange start; latency hides under the
    // poll (wave0 round 1) or bar2 slack (early-arriving idle waves).
    const int tn = (t + 1 < TT) ? t + 1 : t;
    const float xnext = X[tn * 64 + lane];
    if (wave == 1) {
      // publish: ONE coalesced 16-packet burst from wave1 (NOT the poller).
      if (t + 1 < TT && lane < 16) {
        u2v pv; pv.x = pub[lane]; pv.y = tg;
        asm volatile("global_store_dwordx2 %0, %1, off sc0 sc1"
                     :: "v"(slot + 2 * (16 * b + lane)), "v"(pv) : "memory");
      }
    } else if (wave == 0) {
      if (t + 1 < TT) {
        // poll: lane L owns packets {64p+L}; 16 loads in flight per round;
        // vmcnt(0) drains loads only -- no store ever in this wave's queue.
        const unsigned int* b0 = slot + 2 * lane;
        const unsigned int* b1 = b0 + 1024;
        u2v q0, q1, q2, q3, q4, q5, q6, q7, q8, q9, qa, qb, qc, qd, qe, qf;
        for (;;) {
          asm volatile(
              "global_load_dwordx2 %0, %16, off sc0 sc1\n\t"
              "global_load_dwordx2 %1, %16, off offset:512 sc0 sc1\n\t"
              "global_load_dwordx2 %2, %16, off offset:1024 sc0 sc1\n\t"
              "global_load_dwordx2 %3, %16, off offset:1536 sc0 sc1\n\t"
              "global_load_dwordx2 %4, %16, off offset:2048 sc0 sc1\n\t"
              "global_load_dwordx2 %5, %16, off offset:2560 sc0 sc1\n\t"
              "global_load_dwordx2 %6, %16, off offset:3072 sc0 sc1\n\t"
              "global_load_dwordx2 %7, %16, off offset:3584 sc0 sc1\n\t"
              "global_load_dwordx2 %8, %17, off sc0 sc1\n\t"
              "global_load_dwordx2 %9, %17, off offset:512 sc0 sc1\n\t"
              "global_load_dwordx2 %10, %17, off offset:1024 sc0 sc1\n\t"
              "global_load_dwordx2 %11, %17, off offset:1536 sc0 sc1\n\t"
              "global_load_dwordx2 %12, %17, off offset:2048 sc0 sc1\n\t"
              "global_load_dwordx2 %13, %17, off offset:2560 sc0 sc1\n\t"
              "global_load_dwordx2 %14, %17, off offset:3072 sc0 sc1\n\t"
              "global_load_dwordx2 %15, %17, off offset:3584 sc0 sc1\n\t"
              "s_waitcnt vmcnt(0)"
              : "=&v"(q0), "=&v"(q1), "=&v"(q2), "=&v"(q3),
                "=&v"(q4), "=&v"(q5), "=&v"(q6), "=&v"(q7),
                "=&v"(q8), "=&v"(q9), "=&v"(qa), "=&v"(qb),
                "=&v"(qc), "=&v"(qd), "=&v"(qe), "=&v"(qf)
              : "v"(b0), "v"(b1)
              : "memory");
          bool ok = (q0.y == tg) && (q1.y == tg) && (q2.y == tg) &&
                    (q3.y == tg) && (q4.y == tg) && (q5.y == tg) &&
                    (q6.y == tg) && (q7.y == tg) && (q8.y == tg) &&
                    (q9.y == tg) && (qa.y == tg) && (qb.y == tg) &&
                    (qc.y == tg) && (qd.y == tg) && (qe.y == tg) &&
                    (qf.y == tg);
          if (__all(ok)) break;
        }
        // repack: shh[64p + lane] -- stride-1 across lanes, conflict-free
        shh[lane] = q0.x;          shh[64 + lane] = q1.x;
        shh[128 + lane] = q2.x;    shh[192 + lane] = q3.x;
        shh[256 + lane] = q4.x;    shh[320 + lane] = q5.x;
        shh[384 + lane] = q6.x;    shh[448 + lane] = q7.x;
        shh[512 + lane] = q8.x;    shh[576 + lane] = q9.x;
        shh[640 + lane] = qa.x;    shh[704 + lane] = qb.x;
        shh[768 + lane] = qc.x;    shh[832 + lane] = qd.x;
        shh[896 + lane] = qe.x;    shh[960 + lane] = qf.x;
      }
    } else if (tid == 128) {
      // dense partial for step t (wave2 lane0; parallel with publish+poll)
      float s = 0.f;
#pragma unroll
      for (int wv = 0; wv < 16; ++wv) s += psm[wv];
      yp[t * 64 + b] = s;
    }
    __syncthreads();  // bar2: shh now holds h_t (wave1's store ack hidden
                      // here -- wave0's detect-time arrival releases last)
    xv = xnext;
  }
}

__global__ void esn_out(const float* __restrict__ X,
                        const float* __restrict__ wtil,
                        const float* __restrict__ yp,
                        const float* __restrict__ bptr,
                        float* __restrict__ out) {
  const int tid = threadIdx.x;
  const int lane = tid & 63;
  const int wave = tid >> 6;
  const int t = blockIdx.x * 4 + wave;
  float v = wtil[lane] * X[t * 64 + lane] + yp[t * 64 + lane];
#pragma unroll
  for (int off = 32; off; off >>= 1) v += __shfl_xor(v, off, 64);
  if (lane == 0) out[t] = v + bptr[0];
}

extern "C" void kernel_launch(void* const* d_in, const int* in_sizes, int n_in,
                              void* d_out, int out_size, void* d_ws, size_t ws_size,
                              hipStream_t stream) {
  const float* X   = (const float*)d_in[0];
  const float* C   = (const float*)d_in[1];
  const float* Win = (const float*)d_in[2];
  const float* W   = (const float*)d_in[3];
  const float* dW  = (const float*)d_in[4];
  const float* db  = (const float*)d_in[5];
  float* ws   = (float*)d_ws;
  float* M    = ws;
  float* wtil = ws + 131072;
  float* yp   = ws + 131200;
  unsigned int* hpub = (unsigned int*)(ws + 393344);

  esn_prep<<<2049, 64, 0, stream>>>(C, Win, dW, M, wtil);

  void* args[] = {(void*)&X, (void*)&M, (void*)&W, (void*)&dW,
                  (void*)&hpub, (void*)&yp};
  (void)hipLaunchCooperativeKernel(reinterpret_cast<void*>(&esn_recur), dim3(64),
                                   dim3(1024), args, 0, stream);

  esn_out<<<1024, 256, 0, stream>>>(X, wtil, yp, db, (float*)d_out);
}